// Round 13
// baseline (321.036 us; speedup 1.0000x reference)
//
#include <hip/hip_runtime.h>
#include <stdint.h>
#include <math.h>

#define NTOK 8192
#define DIM  512
#define FDIM 2048
#define NEXP 8
#define RMAX 17408   // 136*128 >= 2*NTOK + 8*127 (128-aligned expert offsets)
#define NMT  136
#define O0LO_ROWS 8192   // fp32 output rows [0,8192) alias W1t (dead after gemm1)

typedef __attribute__((ext_vector_type(8))) __bf16 bf16x8;
typedef __attribute__((ext_vector_type(4))) float  f32x4;

// ---------------- gate / prep partition ----------------
#define GTPB 16                    // gate tokens per block (4 waves x 4 sequential)
#define GB_BLOCKS (NTOK / GTPB)    // 512 gate blocks, atomic-free
#define PREP_W1 (GB_BLOCKS)            // [512, 2560): W1 64x64 tiles
#define PREP_W2 (GB_BLOCKS + 2048)     // [2560, 4608): W2 64x64 tiles
#define PREP_TOTAL (GB_BLOCKS + 4096)
#define TROW_PB ((RMAX + GB_BLOCKS - 1) / GB_BLOCKS)   // 34: trow entries zeroed per gate block

// ---------------- workspace layout (bytes), identical to R7-R12 (~150.3 MB, proven) ----------------
#define OFF_W1T    ((size_t)0)
#define SZ_W1T     ((size_t)NEXP * DIM * FDIM * 2)   // 16.78 MB; o rows [0,8192) alias after gemm1
#define OFF_W2T    (OFF_W1T + SZ_W1T)
#define SZ_W2T     SZ_W1T
#define OFF_H      (OFF_W2T + SZ_W2T)
#define SZ_H       ((size_t)RMAX * FDIM * 2)         // 71.3 MB
#define OFF_META   (OFF_H + SZ_H)                    // offsets[9]@0, mtile_e[136]@16
#define SZ_META    ((size_t)1024)
#define OFF_XB     (OFF_META + SZ_META)              // bf16 tokens, token order
#define SZ_XB      ((size_t)NTOK * DIM * 2)          // 8.4 MB
#define OFF_O1     (OFF_XB + SZ_XB)                  // unused (layout kept stable)
#define SZ_O1      ((size_t)RMAX * DIM * 2)
#define OFF_O0HI   (OFF_O1 + SZ_O1)
#define SZ_O0HI    ((size_t)(RMAX - O0LO_ROWS) * DIM * 4)  // 18.9 MB fp32 rows [8192,RMAX)
#define OFF_TROW   (OFF_O0HI + SZ_O0HI)              // [RMAX] int: row -> token
#define OFF_TOKE   (OFF_TROW + (size_t)RMAX * 4)
#define OFF_TOKLS  (OFF_TOKE + (size_t)NTOK * 8)
#define OFF_TOKG   (OFF_TOKLS + (size_t)NTOK * 8)
#define OFF_HISTP  (OFF_TOKG + (size_t)NTOK * 8)     // [512][8] int
#define OFF_BASEP  (OFF_HISTP + (size_t)GB_BLOCKS * NEXP * 4)  // unused (kept for layout stability)
#define OFF_ROWS   (OFF_BASEP + (size_t)GB_BLOCKS * NEXP * 4)  // [NTOK] int2

__device__ __forceinline__ unsigned short f2bf(float f) {
  union { float f; unsigned int u; } v; v.f = f;
  unsigned int u = v.u;
  return (unsigned short)((u + 0x7fffu + ((u >> 16) & 1u)) >> 16);
}
__device__ __forceinline__ float bf2f(unsigned short u) {
  union { unsigned int u; float f; } v; v.u = ((unsigned int)u) << 16;
  return v.f;
}

// async 16B/lane global->LDS; LDS base wave-uniform (HW adds lane*16), global src per-lane
__device__ __forceinline__ void gld16(const unsigned short* g, unsigned short* l) {
  __builtin_amdgcn_global_load_lds(
      (const __attribute__((address_space(1))) void*)g,
      (__attribute__((address_space(3))) void*)l, 16, 0, 0);
}

// ---------------- fused prep: gate+xb+trow0 (front) | transpose W1 | transpose W2 ----------------
__device__ __forceinline__ void transpose_tile64(const float* __restrict__ src,
                                                 unsigned short* __restrict__ dst,
                                                 int R, int C, int bx, int by, int bz) {
  __shared__ float t[64][65];
  const int r0 = by * 64, c0 = bx * 64;
  const float* s = src + (size_t)bz * R * C;
  unsigned short* d = dst + (size_t)bz * R * C;
  const int tr = threadIdx.x >> 6, tc = threadIdx.x & 63;  // tr 0..3
  #pragma unroll
  for (int i = 0; i < 16; i++)
    t[tr + i * 4][tc] = s[(size_t)(r0 + tr + i * 4) * C + (c0 + tc)];
  __syncthreads();
  #pragma unroll
  for (int i = 0; i < 16; i++)
    d[(size_t)(c0 + tr + i * 4) * R + (r0 + tc)] = f2bf(t[tc][tr + i * 4]);
}

// fp64 logits, top-2, softmax; per-block histogram; emits bf16 token rows (xb);
// also zeroes this block's 34-entry slice of trow (pad rows -> token 0, safe)
__device__ __forceinline__ void gate_body(int gb, const float* __restrict__ x,
                            const float* __restrict__ Wg,
                            int* __restrict__ hist_part, int2* __restrict__ tok_e,
                            int2* __restrict__ tok_ls, float2* __restrict__ tok_g,
                            ushort4* __restrict__ xb, int* __restrict__ trow) {
  __shared__ int hist[NEXP];
  __shared__ int le[GTPB][2];
  __shared__ int ls[GTPB][2];
  __shared__ float lg[GTPB][2];
  const int wid = threadIdx.x >> 6;
  const int lane = threadIdx.x & 63;
  if (threadIdx.x < NEXP) hist[threadIdx.x] = 0;
  if (threadIdx.x < TROW_PB) {                 // scan-offload: zero trow slice
    const int i = gb * TROW_PB + threadIdx.x;
    if (i < RMAX) trow[i] = 0;
  }
  __syncthreads();
  for (int t = 0; t < 4; t++) {
    const int lt = wid * 4 + t;
    const int n = gb * GTPB + lt;
    double acc[NEXP];
    #pragma unroll
    for (int e = 0; e < NEXP; e++) acc[e] = 0.0;
    #pragma unroll
    for (int i = 0; i < 8; i++) {
      int dd = lane + i * 64;
      double xv = (double)x[(size_t)n * DIM + dd];
      const float* wr = Wg + (size_t)dd * NEXP;
      #pragma unroll
      for (int e = 0; e < NEXP; e++) acc[e] += xv * (double)wr[e];
    }
    #pragma unroll
    for (int s = 32; s > 0; s >>= 1)
      #pragma unroll
      for (int e = 0; e < NEXP; e++) acc[e] += __shfl_xor(acc[e], s, 64);
    if (lane == 0) {
      int i0 = 0;
      #pragma unroll
      for (int e = 1; e < NEXP; e++) if (acc[e] > acc[i0]) i0 = e;
      int i1 = (i0 == 0) ? 1 : 0;
      #pragma unroll
      for (int e = 0; e < NEXP; e++) { if (e == i0 || e == i1) continue; if (acc[e] > acc[i1]) i1 = e; }
      double e1 = exp(acc[i1] - acc[i0]), ssum = 1.0 + e1;
      le[lt][0] = i0; le[lt][1] = i1;
      ls[lt][0] = atomicAdd(&hist[i0], 1);
      ls[lt][1] = atomicAdd(&hist[i1], 1);
      lg[lt][0] = (float)(1.0 / ssum); lg[lt][1] = (float)(e1 / ssum);
    }
  }
  // bf16 conversion of this block's 16 token rows (x is L1/L2-hot from the logits pass)
  for (int v = threadIdx.x; v < GTPB * (DIM / 4); v += 256) {
    const int lt = v / (DIM / 4), c = v % (DIM / 4);
    const int n = gb * GTPB + lt;
    float4 f = *(const float4*)(x + (size_t)n * DIM + c * 4);
    ushort4 o;
    o.x = f2bf(f.x); o.y = f2bf(f.y); o.z = f2bf(f.z); o.w = f2bf(f.w);
    xb[(size_t)n * (DIM / 4) + c] = o;
  }
  __syncthreads();
  if (threadIdx.x < NEXP) hist_part[gb * NEXP + threadIdx.x] = hist[threadIdx.x];
  if (threadIdx.x < GTPB) {
    const int lt = threadIdx.x;
    const int n = gb * GTPB + lt;
    tok_e[n]  = make_int2(le[lt][0], le[lt][1]);
    tok_ls[n] = make_int2(ls[lt][0], ls[lt][1]);
    tok_g[n]  = make_float2(lg[lt][0], lg[lt][1]);
  }
}

__global__ __launch_bounds__(256) void prep_kernel(const float* __restrict__ W1,
    unsigned short* __restrict__ W1t, const float* __restrict__ W2,
    unsigned short* __restrict__ W2t, const float* __restrict__ x,
    const float* __restrict__ Wg, int* __restrict__ hist_part, int2* __restrict__ tok_e,
    int2* __restrict__ tok_ls, float2* __restrict__ tok_g, ushort4* __restrict__ xb,
    int* __restrict__ trow) {
  const int b = blockIdx.x;
  if (b < GB_BLOCKS) {
    gate_body(b, x, Wg, hist_part, tok_e, tok_ls, tok_g, xb, trow);
  } else if (b < PREP_W2) {        // W1: R=512, C=2048 -> 32 x 8 x 8 tiles of 64x64
    const int q = b - PREP_W1;
    transpose_tile64(W1, W1t, DIM, FDIM, q & 31, (q >> 5) & 7, q >> 8);
  } else {                         // W2: R=2048, C=512 -> 8 x 32 x 8 tiles of 64x64
    const int q = b - PREP_W2;
    transpose_tile64(W2, W2t, FDIM, DIM, q & 7, (q >> 3) & 31, q >> 8);
  }
}

// ---------------- scan+resolve (fused): hist -> offsets/mtile_e AND rows/trow ----------------
// Single block; trow zero-init moved to prep (parallel, free there).
__global__ __launch_bounds__(256) void scan_kernel(const int* __restrict__ hist_part,
    int* __restrict__ offsets, int* __restrict__ mtile_e,
    const int2* __restrict__ tok_e, const int2* __restrict__ tok_ls,
    int2* __restrict__ rows, int* __restrict__ trow) {
  __shared__ int hp[GB_BLOCKS * NEXP];   // 16 KB
  __shared__ int segsum[8][NEXP];
  __shared__ int segbase[8][NEXP];
  __shared__ int tot[NEXP];
  __shared__ int soff[NEXP + 1];
  for (int i = threadIdx.x; i < GB_BLOCKS * NEXP; i += 256) hp[i] = hist_part[i];
  __syncthreads();
  if (threadIdx.x < 64) {
    const int e = threadIdx.x & 7, s = threadIdx.x >> 3;   // 8 segments x 8 experts
    int run = 0;
    for (int b = s * 64; b < s * 64 + 64; b++) {
      int v = hp[b * NEXP + e]; hp[b * NEXP + e] = run; run += v;  // exclusive in-segment
    }
    segsum[s][e] = run;
  }
  __syncthreads();
  if (threadIdx.x < NEXP) {
    const int e = threadIdx.x;
    int run = 0;
    for (int s = 0; s < 8; s++) { segbase[s][e] = run; run += segsum[s][e]; }
    tot[e] = run;
  }
  __syncthreads();
  if (threadIdx.x == 0) {
    int off = 0;
    for (int e = 0; e < NEXP; e++) { soff[e] = off; offsets[e] = off; off += (tot[e] + 127) & ~127; }
    soff[NEXP] = off; offsets[NEXP] = off;
  }
  __syncthreads();
  if (threadIdx.x < NMT) {                     // parallel tile->expert map
    const int r = threadIdx.x * 128;
    int e = NEXP - 1;
    #pragma unroll
    for (int q = 0; q < NEXP; q++)
      if (r >= soff[q] && r < soff[q + 1]) { e = q; break; }
    mtile_e[threadIdx.x] = (r < soff[e] + tot[e]) ? e : -1;   // fully-dead tile skip
  }
  // resolve: token -> 2 rows; row -> token (trow pre-zeroed by prep, stream-ordered)
  for (int n = threadIdx.x; n < NTOK; n += 256) {
    int2 te = tok_e[n]; int2 tl = tok_ls[n];
    const int gb = n >> 4;                     // GTPB = 16
    const int r0 = soff[te.x] + segbase[gb >> 6][te.x] + hp[gb * NEXP + te.x] + tl.x;
    const int r1 = soff[te.y] + segbase[gb >> 6][te.y] + hp[gb * NEXP + te.y] + tl.y;
    rows[n] = make_int2(r0, r1);
    trow[r0] = n;
    trow[r1] = n;
  }
}

// ---------------- 128x128xBK64 single-buffer core (gemm2) -- best measured config ----------------
// 5 blocks/CU (LDS 32KB x 5 = 160KB exact); cross-block TLP hides staging
// latency better than any intra-block pipeline tried (R1/R3/R6). XOR chunk
// swizzle: slot [row][c] holds global chunk c^(row&7). No NT stores (R8).
template <int K, int LDA, int LDB>
__device__ __forceinline__ void gemm_core(const unsigned short* __restrict__ A,
                                          const unsigned short* __restrict__ B,
                                          int m0, int n0, f32x4 acc[4][4]) {
  __shared__ __align__(16) unsigned short As[128 * 64];  // 16 KB
  __shared__ __align__(16) unsigned short Bs[128 * 64];  // 16 KB
  const int tid = threadIdx.x;
  const int wid = tid >> 6, lane = tid & 63;
  const int wm = (wid >> 1) * 64, wn = (wid & 1) * 64;
  const int quad = lane >> 4, l16 = lane & 15;
  const int srow = tid >> 3;                        // 0..31
  const int scol = ((tid & 7) ^ (srow & 7)) << 3;   // swizzled source chunk (elems)
  unsigned short* As_w = As + 512 * wid;            // wave-uniform base
  unsigned short* Bs_w = Bs + 512 * wid;
  const int r7 = (l16 & 7) << 3;                    // read-side swizzle key (elems)
  const unsigned short* Ar = A + (size_t)(m0 + srow) * LDA + scol;
  const unsigned short* Br = B + (size_t)(n0 + srow) * LDB + scol;
  #pragma unroll 1
  for (int kt = 0; kt < K; kt += 64) {
    __syncthreads();                      // prior iteration's LDS reads done
    #pragma unroll
    for (int p = 0; p < 4; p++) {
      gld16(Ar + (size_t)(32 * p) * LDA + kt, As_w + p * 2048);
      gld16(Br + (size_t)(32 * p) * LDB + kt, Bs_w + p * 2048);
    }
    __syncthreads();                      // drains vmcnt before ds_read
    #pragma unroll
    for (int kk = 0; kk < 2; kk++) {
      const int swz = ((kk * 4 + quad) << 3) ^ r7;
      bf16x8 af[4], bfr[4];
      #pragma unroll
      for (int i = 0; i < 4; i++) {
        af[i]  = *(const bf16x8*)(As + (wm + i * 16 + l16) * 64 + swz);
        bfr[i] = *(const bf16x8*)(Bs + (wn + i * 16 + l16) * 64 + swz);
      }
      #pragma unroll
      for (int mi = 0; mi < 4; mi++)
        #pragma unroll
        for (int ni = 0; ni < 4; ni++)
          acc[mi][ni] = __builtin_amdgcn_mfma_f32_16x16x32_bf16(af[mi], bfr[ni], acc[mi][ni], 0, 0, 0);
    }
  }
}

// ---------------- GEMM1: h = relu(xrows @ W1[e] + b1[e]) -> bf16 ----------------
// Grid bn-fast; A-tiles staged directly from token-order xb via trow
// indirection (per-lane global src of global_load_lds).
__global__ __launch_bounds__(256, 5) void gemm1_kernel(const unsigned short* __restrict__ xb,
    const int* __restrict__ trow, const unsigned short* __restrict__ W1t,
    const int* __restrict__ mtile_e, const float* __restrict__ b1,
    unsigned short* __restrict__ h) {
  const int bm = blockIdx.y, bn = blockIdx.x;     // bn fast
  const int e = mtile_e[bm];
  if (e < 0) return;                                // fully-dead (pad) tile
  __shared__ __align__(16) unsigned short As[128 * 64];
  __shared__ __align__(16) unsigned short Bs[128 * 64];
  const int tid = threadIdx.x;
  const int wid = tid >> 6, lane = tid & 63;
  const int wm = (wid >> 1) * 64, wn = (wid & 1) * 64;
  const int quad = lane >> 4, l16 = lane & 15;
  const int srow = tid >> 3;                        // 0..31
  const int scol = ((tid & 7) ^ (srow & 7)) << 3;
  unsigned short* As_w = As + 512 * wid;
  unsigned short* Bs_w = Bs + 512 * wid;
  const int r7 = (l16 & 7) << 3;
  int tokA[4];                                      // row -> token, K-invariant
  #pragma unroll
  for (int p = 0; p < 4; p++) tokA[p] = trow[bm * 128 + 32 * p + srow];
  const unsigned short* Br = W1t + (size_t)e * FDIM * DIM + (size_t)(bn * 128 + srow) * DIM + scol;

  f32x4 acc[4][4];
  #pragma unroll
  for (int i = 0; i < 4; i++)
    #pragma unroll
    for (int j = 0; j < 4; j++) acc[i][j] = (f32x4){0.f, 0.f, 0.f, 0.f};

  #pragma unroll 1
  for (int kt = 0; kt < DIM; kt += 64) {
    __syncthreads();
    #pragma unroll
    for (int p = 0; p < 4; p++) {
      gld16(xb + (size_t)tokA[p] * DIM + scol + kt, As_w + p * 2048);
      gld16(Br + (size_t)(32 * p) * DIM + kt, Bs_w + p * 2048);
    }
    __syncthreads();
    #pragma unroll
    for (int kk = 0; kk < 2; kk++) {
      const int swz = ((kk * 4 + quad) << 3) ^ r7;
      bf16x8 af[4], bfr[4];
      #pragma unroll
      for (int i = 0; i < 4; i++) {
        af[i]  = *(const bf16x8*)(As + (wm + i * 16 + l16) * 64 + swz);
        bfr[i] = *(const bf16x8*)(Bs + (wn + i * 16 + l16) * 64 + swz);
      }
      #pragma unroll
      for (int mi = 0; mi < 4; mi++)
        #pragma unroll
        for (int ni = 0; ni < 4; ni++)
          acc[mi][ni] = __builtin_amdgcn_mfma_f32_16x16x32_bf16(af[mi], bfr[ni], acc[mi][ni], 0, 0, 0);
    }
  }

  #pragma unroll
  for (int mi = 0; mi < 4; mi++) {
    #pragma unroll
    for (int ni = 0; ni < 4; ni++) {
      const int col = bn * 128 + wn + ni * 16 + l16;
      const float bb = b1[e * FDIM + col];
      #pragma unroll
      for (int r = 0; r < 4; r++) {
        const int row = bm * 128 + wm + mi * 16 + quad * 4 + r;
        float v = acc[mi][ni][r] + bb;
        h[(size_t)row * FDIM + col] = f2bf(v > 0.f ? v : 0.f);
      }
    }
  }
}

// ---------------- GEMM2 (KSPLIT=1): o = exp(h @ W2[e] + b2[e]), fp32 ----------------
// exp+bias fused (R12 win, same fp32 op order -> bitwise-identical output).
__global__ __launch_bounds__(256, 5) void gemm2_kernel(const unsigned short* __restrict__ h,
    const unsigned short* __restrict__ W2t, const int* __restrict__ mtile_e,
    const float* __restrict__ b2, float* __restrict__ o0lo, float* __restrict__ o0hi) {
  const int bm = blockIdx.y, bn = blockIdx.x;     // bn fast
  const int e = mtile_e[bm];
  if (e < 0) return;
  f32x4 acc[4][4];
  #pragma unroll
  for (int i = 0; i < 4; i++)
    #pragma unroll
    for (int j = 0; j < 4; j++) acc[i][j] = (f32x4){0.f, 0.f, 0.f, 0.f};
  gemm_core<FDIM, FDIM, FDIM>(h, W2t + (size_t)e * DIM * FDIM, bm * 128, bn * 128, acc);
  const int tid = threadIdx.x, wid = tid >> 6, lane = tid & 63;
  const int wm = (wid >> 1) * 64, wn = (wid & 1) * 64, quad = lane >> 4, l16 = lane & 15;
  // region is block-uniform: tile rows all < 8192 (bm < 64) or all >= 8192
  float* ob = (bm < O0LO_ROWS / 128) ? o0lo : (o0hi - (size_t)O0LO_ROWS * DIM);
  #pragma unroll
  for (int ni = 0; ni < 4; ni++) {
    const int col = bn * 128 + wn + ni * 16 + l16;
    const float bb = b2[e * DIM + col];
    #pragma unroll
    for (int mi = 0; mi < 4; mi++)
      #pragma unroll
      for (int r = 0; r < 4; r++) {
        const int row = bm * 128 + wm + mi * 16 + quad * 4 + r;
        ob[(size_t)row * DIM + col] = __expf(acc[mi][ni][r] + bb);
      }
  }
}

// ---------------- combine: out[n] = log(g0*eo(r0) + g1*eo(r1)) ----------------
__global__ void combine_kernel(const float* __restrict__ o0lo, const float* __restrict__ o0hi,
                               const int2* __restrict__ rows,
                               const float2* __restrict__ tok_g,
                               float* __restrict__ out) {
  const int n = blockIdx.x * 2 + (threadIdx.x >> 7);
  const int c = (threadIdx.x & 127) * 4;
  int2 rr = rows[n]; float2 tg = tok_g[n];
  const int r0 = rr.x, r1 = rr.y;
  const float* p0f = (r0 < O0LO_ROWS) ? (o0lo + (size_t)r0 * DIM)
                                      : (o0hi + (size_t)(r0 - O0LO_ROWS) * DIM);
  const float* p1f = (r1 < O0LO_ROWS) ? (o0lo + (size_t)r1 * DIM)
                                      : (o0hi + (size_t)(r1 - O0LO_ROWS) * DIM);
  float4 a0 = *(const float4*)(p0f + c);
  float4 a1 = *(const float4*)(p1f + c);
  float4 res;
  #pragma unroll
  for (int j = 0; j < 4; j++) {
    float v = tg.x * ((const float*)&a0)[j] + tg.y * ((const float*)&a1)[j];
    v = (v == 0.0f) ? 2.220446049250313e-16f : v;
    ((float*)&res)[j] = __logf(v);
  }
  *(float4*)(out + (size_t)n * DIM + c) = res;
}

extern "C" void kernel_launch(void* const* d_in, const int* in_sizes, int n_in,
                              void* d_out, int out_size, void* d_ws, size_t ws_size,
                              hipStream_t stream) {
  const float* x  = (const float*)d_in[0];
  const float* Wg = (const float*)d_in[1];
  const float* W1 = (const float*)d_in[2];
  const float* b1 = (const float*)d_in[3];
  const float* W2 = (const float*)d_in[4];
  const float* b2 = (const float*)d_in[5];
  float* out = (float*)d_out;
  char* ws = (char*)d_ws;

  unsigned short* W1t = (unsigned short*)(ws + OFF_W1T);
  unsigned short* W2t = (unsigned short*)(ws + OFF_W2T);
  unsigned short* h   = (unsigned short*)(ws + OFF_H);
  int* meta    = (int*)(ws + OFF_META);
  int* offsets = meta;           // [9]
  int* mtile_e = meta + 16;      // [136]
  unsigned short* xb = (unsigned short*)(ws + OFF_XB);
  float* o0lo    = (float*)(ws + OFF_W1T);              // aliases W1t (dead after gemm1)
  float* o0hi    = (float*)(ws + OFF_O0HI);
  int* trow      = (int*)(ws + OFF_TROW);
  int2* tok_e    = (int2*)(ws + OFF_TOKE);
  int2* tok_ls   = (int2*)(ws + OFF_TOKLS);
  float2* tok_g  = (float2*)(ws + OFF_TOKG);
  int* hist_part = (int*)(ws + OFF_HISTP);
  int2* rows     = (int2*)(ws + OFF_ROWS);

  prep_kernel<<<PREP_TOTAL, 256, 0, stream>>>(W1, W1t, W2, W2t, x, Wg,
                                              hist_part, tok_e, tok_ls, tok_g, (ushort4*)xb, trow);
  scan_kernel<<<1, 256, 0, stream>>>(hist_part, offsets, mtile_e, tok_e, tok_ls, rows, trow);
  gemm1_kernel<<<dim3(FDIM / 128, NMT), 256, 0, stream>>>(xb, trow, W1t, mtile_e, b1, h);
  gemm2_kernel<<<dim3(DIM / 128, NMT), 256, 0, stream>>>(h, W2t, mtile_e, b2, o0lo, o0hi);
  combine_kernel<<<NTOK / 2, 256, 0, stream>>>(o0lo, o0hi, rows, tok_g, out);
}

// Round 14
// 264.270 us; speedup vs baseline: 1.2148x; 1.2148x over previous
//
#include <hip/hip_runtime.h>
#include <stdint.h>
#include <math.h>

#define NTOK 8192
#define DIM  512
#define FDIM 2048
#define NEXP 8
#define RMAX 17408   // 136*128 >= 2*NTOK + 8*127 (128-aligned expert offsets)
#define NMT  136
#define O0LO_ROWS 8192   // fp32 output rows [0,8192) alias W1t (dead after gemm1)

typedef __attribute__((ext_vector_type(8))) __bf16 bf16x8;
typedef __attribute__((ext_vector_type(4))) float  f32x4;

// ---------------- gate / prep partition ----------------
#define GTPB 16                    // gate tokens per block (4 waves x 4 sequential)
#define GB_BLOCKS (NTOK / GTPB)    // 512 gate blocks, atomic-free
#define PREP_W1 (GB_BLOCKS)            // [512, 2560): W1 64x64 tiles
#define PREP_W2 (GB_BLOCKS + 2048)     // [2560, 4608): W2 64x64 tiles
#define PREP_TOTAL (GB_BLOCKS + 4096)
#define TROW_PB ((RMAX + GB_BLOCKS - 1) / GB_BLOCKS)   // 34: trow entries zeroed per gate block

// ---------------- workspace layout (bytes), identical to R7-R13 (~150.3 MB, proven) ----------------
#define OFF_W1T    ((size_t)0)
#define SZ_W1T     ((size_t)NEXP * DIM * FDIM * 2)   // 16.78 MB; o rows [0,8192) alias after gemm1
#define OFF_W2T    (OFF_W1T + SZ_W1T)
#define SZ_W2T     SZ_W1T
#define OFF_H      (OFF_W2T + SZ_W2T)
#define SZ_H       ((size_t)RMAX * FDIM * 2)         // 71.3 MB
#define OFF_META   (OFF_H + SZ_H)                    // offsets[9]@0, mtile_e[136]@16
#define SZ_META    ((size_t)1024)
#define OFF_XB     (OFF_META + SZ_META)              // bf16 tokens, token order
#define SZ_XB      ((size_t)NTOK * DIM * 2)          // 8.4 MB
#define OFF_O1     (OFF_XB + SZ_XB)                  // unused (layout kept stable)
#define SZ_O1      ((size_t)RMAX * DIM * 2)
#define OFF_O0HI   (OFF_O1 + SZ_O1)
#define SZ_O0HI    ((size_t)(RMAX - O0LO_ROWS) * DIM * 4)  // 18.9 MB fp32 rows [8192,RMAX)
#define OFF_TROW   (OFF_O0HI + SZ_O0HI)              // [RMAX] int: row -> token
#define OFF_TOKE   (OFF_TROW + (size_t)RMAX * 4)
#define OFF_TOKLS  (OFF_TOKE + (size_t)NTOK * 8)
#define OFF_TOKG   (OFF_TOKLS + (size_t)NTOK * 8)
#define OFF_HISTP  (OFF_TOKG + (size_t)NTOK * 8)     // [512][8] int
#define OFF_BASEP  (OFF_HISTP + (size_t)GB_BLOCKS * NEXP * 4)  // unused (kept for layout stability)
#define OFF_ROWS   (OFF_BASEP + (size_t)GB_BLOCKS * NEXP * 4)  // [NTOK] int2

__device__ __forceinline__ unsigned short f2bf(float f) {
  union { float f; unsigned int u; } v; v.f = f;
  unsigned int u = v.u;
  return (unsigned short)((u + 0x7fffu + ((u >> 16) & 1u)) >> 16);
}
__device__ __forceinline__ float bf2f(unsigned short u) {
  union { unsigned int u; float f; } v; v.u = ((unsigned int)u) << 16;
  return v.f;
}

// async 16B/lane global->LDS; LDS base wave-uniform (HW adds lane*16), global src per-lane
__device__ __forceinline__ void gld16(const unsigned short* g, unsigned short* l) {
  __builtin_amdgcn_global_load_lds(
      (const __attribute__((address_space(1))) void*)g,
      (__attribute__((address_space(3))) void*)l, 16, 0, 0);
}

// ---------------- fused prep: gate+xb+trow0 (front) | transpose W1 | transpose W2 ----------------
__device__ __forceinline__ void transpose_tile64(const float* __restrict__ src,
                                                 unsigned short* __restrict__ dst,
                                                 int R, int C, int bx, int by, int bz) {
  __shared__ float t[64][65];
  const int r0 = by * 64, c0 = bx * 64;
  const float* s = src + (size_t)bz * R * C;
  unsigned short* d = dst + (size_t)bz * R * C;
  const int tr = threadIdx.x >> 6, tc = threadIdx.x & 63;  // tr 0..3
  #pragma unroll
  for (int i = 0; i < 16; i++)
    t[tr + i * 4][tc] = s[(size_t)(r0 + tr + i * 4) * C + (c0 + tc)];
  __syncthreads();
  #pragma unroll
  for (int i = 0; i < 16; i++)
    d[(size_t)(c0 + tr + i * 4) * R + (r0 + tc)] = f2bf(t[tc][tr + i * 4]);
}

// fp64 logits, top-2, softmax; per-block histogram; emits bf16 token rows (xb);
// also zeroes this block's 34-entry slice of trow (pad rows -> token 0, safe)
__device__ __forceinline__ void gate_body(int gb, const float* __restrict__ x,
                            const float* __restrict__ Wg,
                            int* __restrict__ hist_part, int2* __restrict__ tok_e,
                            int2* __restrict__ tok_ls, float2* __restrict__ tok_g,
                            ushort4* __restrict__ xb, int* __restrict__ trow) {
  __shared__ int hist[NEXP];
  __shared__ int le[GTPB][2];
  __shared__ int ls[GTPB][2];
  __shared__ float lg[GTPB][2];
  const int wid = threadIdx.x >> 6;
  const int lane = threadIdx.x & 63;
  if (threadIdx.x < NEXP) hist[threadIdx.x] = 0;
  if (threadIdx.x < TROW_PB) {                 // scan-offload: zero trow slice
    const int i = gb * TROW_PB + threadIdx.x;
    if (i < RMAX) trow[i] = 0;
  }
  __syncthreads();
  for (int t = 0; t < 4; t++) {
    const int lt = wid * 4 + t;
    const int n = gb * GTPB + lt;
    double acc[NEXP];
    #pragma unroll
    for (int e = 0; e < NEXP; e++) acc[e] = 0.0;
    #pragma unroll
    for (int i = 0; i < 8; i++) {
      int dd = lane + i * 64;
      double xv = (double)x[(size_t)n * DIM + dd];
      const float* wr = Wg + (size_t)dd * NEXP;
      #pragma unroll
      for (int e = 0; e < NEXP; e++) acc[e] += xv * (double)wr[e];
    }
    #pragma unroll
    for (int s = 32; s > 0; s >>= 1)
      #pragma unroll
      for (int e = 0; e < NEXP; e++) acc[e] += __shfl_xor(acc[e], s, 64);
    if (lane == 0) {
      int i0 = 0;
      #pragma unroll
      for (int e = 1; e < NEXP; e++) if (acc[e] > acc[i0]) i0 = e;
      int i1 = (i0 == 0) ? 1 : 0;
      #pragma unroll
      for (int e = 0; e < NEXP; e++) { if (e == i0 || e == i1) continue; if (acc[e] > acc[i1]) i1 = e; }
      double e1 = exp(acc[i1] - acc[i0]), ssum = 1.0 + e1;
      le[lt][0] = i0; le[lt][1] = i1;
      ls[lt][0] = atomicAdd(&hist[i0], 1);
      ls[lt][1] = atomicAdd(&hist[i1], 1);
      lg[lt][0] = (float)(1.0 / ssum); lg[lt][1] = (float)(e1 / ssum);
    }
  }
  // bf16 conversion of this block's 16 token rows (x is L1/L2-hot from the logits pass)
  for (int v = threadIdx.x; v < GTPB * (DIM / 4); v += 256) {
    const int lt = v / (DIM / 4), c = v % (DIM / 4);
    const int n = gb * GTPB + lt;
    float4 f = *(const float4*)(x + (size_t)n * DIM + c * 4);
    ushort4 o;
    o.x = f2bf(f.x); o.y = f2bf(f.y); o.z = f2bf(f.z); o.w = f2bf(f.w);
    xb[(size_t)n * (DIM / 4) + c] = o;
  }
  __syncthreads();
  if (threadIdx.x < NEXP) hist_part[gb * NEXP + threadIdx.x] = hist[threadIdx.x];
  if (threadIdx.x < GTPB) {
    const int lt = threadIdx.x;
    const int n = gb * GTPB + lt;
    tok_e[n]  = make_int2(le[lt][0], le[lt][1]);
    tok_ls[n] = make_int2(ls[lt][0], ls[lt][1]);
    tok_g[n]  = make_float2(lg[lt][0], lg[lt][1]);
  }
}

__global__ __launch_bounds__(256) void prep_kernel(const float* __restrict__ W1,
    unsigned short* __restrict__ W1t, const float* __restrict__ W2,
    unsigned short* __restrict__ W2t, const float* __restrict__ x,
    const float* __restrict__ Wg, int* __restrict__ hist_part, int2* __restrict__ tok_e,
    int2* __restrict__ tok_ls, float2* __restrict__ tok_g, ushort4* __restrict__ xb,
    int* __restrict__ trow) {
  const int b = blockIdx.x;
  if (b < GB_BLOCKS) {
    gate_body(b, x, Wg, hist_part, tok_e, tok_ls, tok_g, xb, trow);
  } else if (b < PREP_W2) {        // W1: R=512, C=2048 -> 32 x 8 x 8 tiles of 64x64
    const int q = b - PREP_W1;
    transpose_tile64(W1, W1t, DIM, FDIM, q & 31, (q >> 5) & 7, q >> 8);
  } else {                         // W2: R=2048, C=512 -> 8 x 32 x 8 tiles of 64x64
    const int q = b - PREP_W2;
    transpose_tile64(W2, W2t, FDIM, DIM, q & 7, (q >> 3) & 31, q >> 8);
  }
}

// ---------------- scan+resolve (fused): hist -> offsets/mtile_e AND rows/trow ----------------
// Single block; trow zero-init done by prep (parallel, free there).
__global__ __launch_bounds__(256) void scan_kernel(const int* __restrict__ hist_part,
    int* __restrict__ offsets, int* __restrict__ mtile_e,
    const int2* __restrict__ tok_e, const int2* __restrict__ tok_ls,
    int2* __restrict__ rows, int* __restrict__ trow) {
  __shared__ int hp[GB_BLOCKS * NEXP];   // 16 KB
  __shared__ int segsum[8][NEXP];
  __shared__ int segbase[8][NEXP];
  __shared__ int tot[NEXP];
  __shared__ int soff[NEXP + 1];
  for (int i = threadIdx.x; i < GB_BLOCKS * NEXP; i += 256) hp[i] = hist_part[i];
  __syncthreads();
  if (threadIdx.x < 64) {
    const int e = threadIdx.x & 7, s = threadIdx.x >> 3;   // 8 segments x 8 experts
    int run = 0;
    for (int b = s * 64; b < s * 64 + 64; b++) {
      int v = hp[b * NEXP + e]; hp[b * NEXP + e] = run; run += v;  // exclusive in-segment
    }
    segsum[s][e] = run;
  }
  __syncthreads();
  if (threadIdx.x < NEXP) {
    const int e = threadIdx.x;
    int run = 0;
    for (int s = 0; s < 8; s++) { segbase[s][e] = run; run += segsum[s][e]; }
    tot[e] = run;
  }
  __syncthreads();
  if (threadIdx.x == 0) {
    int off = 0;
    for (int e = 0; e < NEXP; e++) { soff[e] = off; offsets[e] = off; off += (tot[e] + 127) & ~127; }
    soff[NEXP] = off; offsets[NEXP] = off;
  }
  __syncthreads();
  if (threadIdx.x < NMT) {                     // parallel tile->expert map
    const int r = threadIdx.x * 128;
    int e = NEXP - 1;
    #pragma unroll
    for (int q = 0; q < NEXP; q++)
      if (r >= soff[q] && r < soff[q + 1]) { e = q; break; }
    mtile_e[threadIdx.x] = (r < soff[e] + tot[e]) ? e : -1;   // fully-dead tile skip
  }
  // resolve: token -> 2 rows; row -> token (trow pre-zeroed by prep, stream-ordered)
  for (int n = threadIdx.x; n < NTOK; n += 256) {
    int2 te = tok_e[n]; int2 tl = tok_ls[n];
    const int gb = n >> 4;                     // GTPB = 16
    const int r0 = soff[te.x] + segbase[gb >> 6][te.x] + hp[gb * NEXP + te.x] + tl.x;
    const int r1 = soff[te.y] + segbase[gb >> 6][te.y] + hp[gb * NEXP + te.y] + tl.y;
    rows[n] = make_int2(r0, r1);
    trow[r0] = n;
    trow[r1] = n;
  }
}

// ---------------- 128x128xBK64 single-buffer core (gemm2) -- best measured config ----------------
// launch_bounds(256,4): VGPR budget 56-60 fits with NO spills. R13 measured
// (256,5): regalloc squeezed to 48 VGPR -> accumulator spills -> WRITE_SIZE
// 34.5->108 MB, gemm2 60.6->100.4 us. Register file, not LDS, is the
// occupancy limit at this block shape; 4 blocks/CU is the ceiling.
// XOR chunk swizzle: slot [row][c] holds global chunk c^(row&7). No NT
// stores (R8: partial-line NT ~2x HBM writes).
template <int K, int LDA, int LDB>
__device__ __forceinline__ void gemm_core(const unsigned short* __restrict__ A,
                                          const unsigned short* __restrict__ B,
                                          int m0, int n0, f32x4 acc[4][4]) {
  __shared__ __align__(16) unsigned short As[128 * 64];  // 16 KB
  __shared__ __align__(16) unsigned short Bs[128 * 64];  // 16 KB
  const int tid = threadIdx.x;
  const int wid = tid >> 6, lane = tid & 63;
  const int wm = (wid >> 1) * 64, wn = (wid & 1) * 64;
  const int quad = lane >> 4, l16 = lane & 15;
  const int srow = tid >> 3;                        // 0..31
  const int scol = ((tid & 7) ^ (srow & 7)) << 3;   // swizzled source chunk (elems)
  unsigned short* As_w = As + 512 * wid;            // wave-uniform base
  unsigned short* Bs_w = Bs + 512 * wid;
  const int r7 = (l16 & 7) << 3;                    // read-side swizzle key (elems)
  const unsigned short* Ar = A + (size_t)(m0 + srow) * LDA + scol;
  const unsigned short* Br = B + (size_t)(n0 + srow) * LDB + scol;
  #pragma unroll 1
  for (int kt = 0; kt < K; kt += 64) {
    __syncthreads();                      // prior iteration's LDS reads done
    #pragma unroll
    for (int p = 0; p < 4; p++) {
      gld16(Ar + (size_t)(32 * p) * LDA + kt, As_w + p * 2048);
      gld16(Br + (size_t)(32 * p) * LDB + kt, Bs_w + p * 2048);
    }
    __syncthreads();                      // drains vmcnt before ds_read
    #pragma unroll
    for (int kk = 0; kk < 2; kk++) {
      const int swz = ((kk * 4 + quad) << 3) ^ r7;
      bf16x8 af[4], bfr[4];
      #pragma unroll
      for (int i = 0; i < 4; i++) {
        af[i]  = *(const bf16x8*)(As + (wm + i * 16 + l16) * 64 + swz);
        bfr[i] = *(const bf16x8*)(Bs + (wn + i * 16 + l16) * 64 + swz);
      }
      #pragma unroll
      for (int mi = 0; mi < 4; mi++)
        #pragma unroll
        for (int ni = 0; ni < 4; ni++)
          acc[mi][ni] = __builtin_amdgcn_mfma_f32_16x16x32_bf16(af[mi], bfr[ni], acc[mi][ni], 0, 0, 0);
    }
  }
}

// ---------------- GEMM1: h = relu(xrows @ W1[e] + b1[e]) -> bf16 ----------------
// Grid bn-fast; A-tiles staged directly from token-order xb via trow
// indirection (per-lane global src of global_load_lds).
__global__ __launch_bounds__(256, 4) void gemm1_kernel(const unsigned short* __restrict__ xb,
    const int* __restrict__ trow, const unsigned short* __restrict__ W1t,
    const int* __restrict__ mtile_e, const float* __restrict__ b1,
    unsigned short* __restrict__ h) {
  const int bm = blockIdx.y, bn = blockIdx.x;     // bn fast
  const int e = mtile_e[bm];
  if (e < 0) return;                                // fully-dead (pad) tile
  __shared__ __align__(16) unsigned short As[128 * 64];
  __shared__ __align__(16) unsigned short Bs[128 * 64];
  const int tid = threadIdx.x;
  const int wid = tid >> 6, lane = tid & 63;
  const int wm = (wid >> 1) * 64, wn = (wid & 1) * 64;
  const int quad = lane >> 4, l16 = lane & 15;
  const int srow = tid >> 3;                        // 0..31
  const int scol = ((tid & 7) ^ (srow & 7)) << 3;
  unsigned short* As_w = As + 512 * wid;
  unsigned short* Bs_w = Bs + 512 * wid;
  const int r7 = (l16 & 7) << 3;
  int tokA[4];                                      // row -> token, K-invariant
  #pragma unroll
  for (int p = 0; p < 4; p++) tokA[p] = trow[bm * 128 + 32 * p + srow];
  const unsigned short* Br = W1t + (size_t)e * FDIM * DIM + (size_t)(bn * 128 + srow) * DIM + scol;

  f32x4 acc[4][4];
  #pragma unroll
  for (int i = 0; i < 4; i++)
    #pragma unroll
    for (int j = 0; j < 4; j++) acc[i][j] = (f32x4){0.f, 0.f, 0.f, 0.f};

  #pragma unroll 1
  for (int kt = 0; kt < DIM; kt += 64) {
    __syncthreads();
    #pragma unroll
    for (int p = 0; p < 4; p++) {
      gld16(xb + (size_t)tokA[p] * DIM + scol + kt, As_w + p * 2048);
      gld16(Br + (size_t)(32 * p) * DIM + kt, Bs_w + p * 2048);
    }
    __syncthreads();
    #pragma unroll
    for (int kk = 0; kk < 2; kk++) {
      const int swz = ((kk * 4 + quad) << 3) ^ r7;
      bf16x8 af[4], bfr[4];
      #pragma unroll
      for (int i = 0; i < 4; i++) {
        af[i]  = *(const bf16x8*)(As + (wm + i * 16 + l16) * 64 + swz);
        bfr[i] = *(const bf16x8*)(Bs + (wn + i * 16 + l16) * 64 + swz);
      }
      #pragma unroll
      for (int mi = 0; mi < 4; mi++)
        #pragma unroll
        for (int ni = 0; ni < 4; ni++)
          acc[mi][ni] = __builtin_amdgcn_mfma_f32_16x16x32_bf16(af[mi], bfr[ni], acc[mi][ni], 0, 0, 0);
    }
  }

  #pragma unroll
  for (int mi = 0; mi < 4; mi++) {
    #pragma unroll
    for (int ni = 0; ni < 4; ni++) {
      const int col = bn * 128 + wn + ni * 16 + l16;
      const float bb = b1[e * FDIM + col];
      #pragma unroll
      for (int r = 0; r < 4; r++) {
        const int row = bm * 128 + wm + mi * 16 + quad * 4 + r;
        float v = acc[mi][ni][r] + bb;
        h[(size_t)row * FDIM + col] = f2bf(v > 0.f ? v : 0.f);
      }
    }
  }
}

// ---------------- GEMM2 (KSPLIT=1): o = exp(h @ W2[e] + b2[e]), fp32 ----------------
// exp+bias fused (R12 win, same fp32 op order -> bitwise-identical output).
__global__ __launch_bounds__(256, 4) void gemm2_kernel(const unsigned short* __restrict__ h,
    const unsigned short* __restrict__ W2t, const int* __restrict__ mtile_e,
    const float* __restrict__ b2, float* __restrict__ o0lo, float* __restrict__ o0hi) {
  const int bm = blockIdx.y, bn = blockIdx.x;     // bn fast
  const int e = mtile_e[bm];
  if (e < 0) return;
  f32x4 acc[4][4];
  #pragma unroll
  for (int i = 0; i < 4; i++)
    #pragma unroll
    for (int j = 0; j < 4; j++) acc[i][j] = (f32x4){0.f, 0.f, 0.f, 0.f};
  gemm_core<FDIM, FDIM, FDIM>(h, W2t + (size_t)e * DIM * FDIM, bm * 128, bn * 128, acc);
  const int tid = threadIdx.x, wid = tid >> 6, lane = tid & 63;
  const int wm = (wid >> 1) * 64, wn = (wid & 1) * 64, quad = lane >> 4, l16 = lane & 15;
  // region is block-uniform: tile rows all < 8192 (bm < 64) or all >= 8192
  float* ob = (bm < O0LO_ROWS / 128) ? o0lo : (o0hi - (size_t)O0LO_ROWS * DIM);
  #pragma unroll
  for (int ni = 0; ni < 4; ni++) {
    const int col = bn * 128 + wn + ni * 16 + l16;
    const float bb = b2[e * DIM + col];
    #pragma unroll
    for (int mi = 0; mi < 4; mi++)
      #pragma unroll
      for (int r = 0; r < 4; r++) {
        const int row = bm * 128 + wm + mi * 16 + quad * 4 + r;
        ob[(size_t)row * DIM + col] = __expf(acc[mi][ni][r] + bb);
      }
  }
}

// ---------------- combine: out[n] = log(g0*eo(r0) + g1*eo(r1)) ----------------
__global__ void combine_kernel(const float* __restrict__ o0lo, const float* __restrict__ o0hi,
                               const int2* __restrict__ rows,
                               const float2* __restrict__ tok_g,
                               float* __restrict__ out) {
  const int n = blockIdx.x * 2 + (threadIdx.x >> 7);
  const int c = (threadIdx.x & 127) * 4;
  int2 rr = rows[n]; float2 tg = tok_g[n];
  const int r0 = rr.x, r1 = rr.y;
  const float* p0f = (r0 < O0LO_ROWS) ? (o0lo + (size_t)r0 * DIM)
                                      : (o0hi + (size_t)(r0 - O0LO_ROWS) * DIM);
  const float* p1f = (r1 < O0LO_ROWS) ? (o0lo + (size_t)r1 * DIM)
                                      : (o0hi + (size_t)(r1 - O0LO_ROWS) * DIM);
  float4 a0 = *(const float4*)(p0f + c);
  float4 a1 = *(const float4*)(p1f + c);
  float4 res;
  #pragma unroll
  for (int j = 0; j < 4; j++) {
    float v = tg.x * ((const float*)&a0)[j] + tg.y * ((const float*)&a1)[j];
    v = (v == 0.0f) ? 2.220446049250313e-16f : v;
    ((float*)&res)[j] = __logf(v);
  }
  *(float4*)(out + (size_t)n * DIM + c) = res;
}

extern "C" void kernel_launch(void* const* d_in, const int* in_sizes, int n_in,
                              void* d_out, int out_size, void* d_ws, size_t ws_size,
                              hipStream_t stream) {
  const float* x  = (const float*)d_in[0];
  const float* Wg = (const float*)d_in[1];
  const float* W1 = (const float*)d_in[2];
  const float* b1 = (const float*)d_in[3];
  const float* W2 = (const float*)d_in[4];
  const float* b2 = (const float*)d_in[5];
  float* out = (float*)d_out;
  char* ws = (char*)d_ws;

  unsigned short* W1t = (unsigned short*)(ws + OFF_W1T);
  unsigned short* W2t = (unsigned short*)(ws + OFF_W2T);
  unsigned short* h   = (unsigned short*)(ws + OFF_H);
  int* meta    = (int*)(ws + OFF_META);
  int* offsets = meta;           // [9]
  int* mtile_e = meta + 16;      // [136]
  unsigned short* xb = (unsigned short*)(ws + OFF_XB);
  float* o0lo    = (float*)(ws + OFF_W1T);              // aliases W1t (dead after gemm1)
  float* o0hi    = (float*)(ws + OFF_O0HI);
  int* trow      = (int*)(ws + OFF_TROW);
  int2* tok_e    = (int2*)(ws + OFF_TOKE);
  int2* tok_ls   = (int2*)(ws + OFF_TOKLS);
  float2* tok_g  = (float2*)(ws + OFF_TOKG);
  int* hist_part = (int*)(ws + OFF_HISTP);
  int2* rows     = (int2*)(ws + OFF_ROWS);

  prep_kernel<<<PREP_TOTAL, 256, 0, stream>>>(W1, W1t, W2, W2t, x, Wg,
                                              hist_part, tok_e, tok_ls, tok_g, (ushort4*)xb, trow);
  scan_kernel<<<1, 256, 0, stream>>>(hist_part, offsets, mtile_e, tok_e, tok_ls, rows, trow);
  gemm1_kernel<<<dim3(FDIM / 128, NMT), 256, 0, stream>>>(xb, trow, W1t, mtile_e, b1, h);
  gemm2_kernel<<<dim3(DIM / 128, NMT), 256, 0, stream>>>(h, W2t, mtile_e, b2, o0lo, o0hi);
  combine_kernel<<<NTOK / 2, 256, 0, stream>>>(o0lo, o0hi, rows, tok_g, out);
}